// Round 12
// baseline (327.007 us; speedup 1.0000x reference)
//
#include <hip/hip_runtime.h>
#include <math.h>

#define N_NODES 100000
#define C 64
#define EPS 1e-9f
#define SCAN_BLK 1024
#define NXCD 8
#define NG 4
#define RNG (N_NODES / NG)            // 25000 src rows per g-bucket
#define SLICE_N (N_NODES / NXCD)      // 12500 dst rows per slice
#define KEYS (N_NODES * NG)           // 400000 (dst,g) keys == position count
#define NBLKK ((KEYS + SCAN_BLK - 1) / SCAN_BLK)   // 391
#define GCH 500
#define GPB 25                        // groups per block (GCH*GPB*8 == N_NODES)
#define NDH ((N_NODES + 255) / 256)   // 391 blocks for per-node kernels
#define NBINS 1024                    // [g][dst-slice][class] = 4*8*32

typedef __attribute__((ext_vector_type(8))) short bf16x8;
typedef __attribute__((ext_vector_type(8))) unsigned short u16x8;
typedef __attribute__((ext_vector_type(4))) float f32x4;
typedef unsigned short u16;
typedef unsigned int u32;

__device__ __forceinline__ u16 f2bf(float f) {
    union { float f; u32 u; } v; v.f = f;
    u32 u = v.u;
    return (u16)((u + 0x7FFFu + ((u >> 16) & 1u)) >> 16);
}
__device__ __forceinline__ float bf2f(u16 b) {
    union { u32 u; float f; } v; v.u = (u32)b << 16;
    return v.f;
}

// ===========================================================================
// Scan kernels. scan_block_perm reads the per-position count on the fly:
// cperm[p] = cnt2[4*ord[p] + p/N].
// ===========================================================================
__global__ void scan_block_perm_kernel(const int* __restrict__ ord,
                                       const int* __restrict__ cnt2,
                                       int* __restrict__ off,
                                       int* __restrict__ bsum, int n) {
    __shared__ int tmp[SCAN_BLK];
    int tid = threadIdx.x;
    int gid = blockIdx.x * SCAN_BLK + tid;
    int v = 0;
    if (gid < n) {
        int g = gid / N_NODES;
        v = cnt2[4 * ord[gid] + g];
    }
    tmp[tid] = v;
    __syncthreads();
    for (int d = 1; d < SCAN_BLK; d <<= 1) {
        int t = (tid >= d) ? tmp[tid - d] : 0;
        __syncthreads();
        tmp[tid] += t;
        __syncthreads();
    }
    if (gid < n) off[gid] = tmp[tid] - v;
    if (tid == SCAN_BLK - 1) bsum[blockIdx.x] = tmp[tid];
}

__global__ void scan_bsum_kernel(int* __restrict__ bsum, int nb) {
    __shared__ int tmp[512];
    int tid = threadIdx.x;
    int v = (tid < nb) ? bsum[tid] : 0;
    tmp[tid] = v;
    __syncthreads();
    for (int d = 1; d < 512; d <<= 1) {
        int t = (tid >= d) ? tmp[tid - d] : 0;
        __syncthreads();
        tmp[tid] += t;
        __syncthreads();
    }
    if (tid < nb) bsum[tid] = tmp[tid] - v;
}

__global__ void scan_add_kernel(int* __restrict__ off, const int* __restrict__ bsum,
                                int n, int E) {
    int gid = blockIdx.x * SCAN_BLK + threadIdx.x;
    if (gid < n) off[gid] += bsum[blockIdx.x];
    if (gid == 0) off[n] = E;
}

// ===========================================================================
// K0: partition edges into 8 dst-range buckets (per-slice (key16,src) arrays)
// ===========================================================================
__global__ void __launch_bounds__(256)
partition_kernel(const int* __restrict__ src, const int* __restrict__ dst,
                 int* __restrict__ bcur, u16* __restrict__ bkey16,
                 int* __restrict__ bsrc, int E, int bcap) {
    __shared__ int lcnt[NXCD];
    __shared__ int lbase[NXCD];
    const int tid = threadIdx.x;
    const int per = (E + gridDim.x - 1) / gridDim.x;
    const int i0 = blockIdx.x * per;
    const int i1 = min(i0 + per, E);

    if (tid < NXCD) lcnt[tid] = 0;
    __syncthreads();
    for (int i = i0 + tid; i < i1; i += 256)
        atomicAdd(&lcnt[dst[i] / SLICE_N], 1);
    __syncthreads();
    if (tid < NXCD) {
        lbase[tid] = atomicAdd(&bcur[tid], lcnt[tid]);
        lcnt[tid] = 0;
    }
    __syncthreads();
    for (int i = i0 + tid; i < i1; i += 256) {
        int d  = dst[i];
        int sv = src[i];
        int s  = d / SLICE_N;
        int p  = lbase[s] + atomicAdd(&lcnt[s], 1);
        size_t pos = (size_t)s * bcap + p;
        bkey16[pos] = (u16)((d - s * SLICE_N) * NG + sv / RNG);
        bsrc[pos] = sv;
    }
}

// hist over bucketed keys; slice-s atomics stay in a 200KB XCD-local region.
__global__ void hist2p_kernel(const int* __restrict__ bcur,
                              const u16* __restrict__ bkey16,
                              int* __restrict__ cnt2, int bcap) {
    const int s = blockIdx.x & (NXCD - 1);
    const int bn = bcur[s];
    const u16* __restrict__ k = bkey16 + (size_t)s * bcap;
    int* __restrict__ c2 = cnt2 + s * (SLICE_N * NG);
    const int stride = (gridDim.x >> 3) * blockDim.x;
    for (int i = (blockIdx.x >> 3) * blockDim.x + threadIdx.x; i < bn; i += stride)
        atomicAdd(&c2[k[i]], 1);
}

// time-blocked build pass: classes in [clo,chi); class read from XCD-local cnt2.
__global__ void __launch_bounds__(256)
build_pass_kernel(const int* __restrict__ bcur, const u16* __restrict__ bkey16,
                  const int* __restrict__ bsrc, const int* __restrict__ cnt2,
                  int* __restrict__ cursor2, int* __restrict__ csr,
                  int bcap, int clo, int chi) {
    const int s = blockIdx.x & (NXCD - 1);
    const int bn = bcur[s];
    const u16* __restrict__ k  = bkey16 + (size_t)s * bcap;
    const int* __restrict__ sv = bsrc + (size_t)s * bcap;
    const int* __restrict__ c2 = cnt2 + s * (SLICE_N * NG);
    int* __restrict__ cur = cursor2 + s * (SLICE_N * NG);
    const int stride = (gridDim.x >> 3) * blockDim.x;
    for (int i = (blockIdx.x >> 3) * blockDim.x + threadIdx.x; i < bn; i += stride) {
        int kk = k[i];
        int c = min(c2[kk], 31);
        if (c >= clo && c < chi) {
            int p = atomicAdd(&cur[kk], 1);
            csr[p] = sv[i];
        }
    }
}

// Tier-B hist/build (no bucket arrays): direct 8x edge-list streaming
__global__ void hist2_kernel(const int* __restrict__ src, const int* __restrict__ dst,
                             int* __restrict__ cnt2, int E) {
    const int s  = blockIdx.x & (NXCD - 1);
    const int lo = s * SLICE_N;
    const int hi = lo + SLICE_N;
    const int stride = (gridDim.x >> 3) * blockDim.x;
    for (int i = (blockIdx.x >> 3) * blockDim.x + threadIdx.x; i < E; i += stride) {
        int d = dst[i];
        if (d >= lo && d < hi) {
            int g = src[i] / RNG;
            atomicAdd(&cnt2[d * NG + g], 1);
        }
    }
}

__global__ void build2_kernel(const int* __restrict__ src, const int* __restrict__ dst,
                              int* __restrict__ cursor2, int* __restrict__ csr, int E) {
    const int s  = blockIdx.x & (NXCD - 1);
    const int lo = s * SLICE_N;
    const int hi = lo + SLICE_N;
    const int stride = (gridDim.x >> 3) * blockDim.x;
    for (int i = (blockIdx.x >> 3) * blockDim.x + threadIdx.x; i < E; i += stride) {
        int d = dst[i];
        if (d >= lo && d < hi) {
            int sv = src[i];
            int g = sv / RNG;
            int p = atomicAdd(&cursor2[d * NG + g], 1);
            csr[p] = sv;
        }
    }
}

// ===========================================================================
// Slice-local degree-class ordering: bins = [g][dst-slice][class] (g-major).
// ===========================================================================
__global__ void __launch_bounds__(256)
deg_class_kernel(const int* __restrict__ cnt2, int* __restrict__ dh,
                 int* __restrict__ degT) {
    __shared__ int lh[NBINS];
    const int tid = threadIdx.x;
    for (int i = tid; i < NBINS; i += 256) lh[i] = 0;
    __syncthreads();
    const int n = blockIdx.x * 256 + tid;
    if (n < N_NODES) {
        int4 c4 = *(const int4*)(cnt2 + 4 * n);
        degT[n] = c4.x + c4.y + c4.z + c4.w;
        const int sb = (n / SLICE_N) * 32;
        atomicAdd(&lh[0 * 256 + sb + min(c4.x, 31)], 1);
        atomicAdd(&lh[1 * 256 + sb + min(c4.y, 31)], 1);
        atomicAdd(&lh[2 * 256 + sb + min(c4.z, 31)], 1);
        atomicAdd(&lh[3 * 256 + sb + min(c4.w, 31)], 1);
    }
    __syncthreads();
    for (int i = tid; i < NBINS; i += 256)
        if (lh[i]) atomicAdd(&dh[i], lh[i]);
}

__global__ void __launch_bounds__(NBINS)
scan_deg_kernel(int* __restrict__ dh, int* __restrict__ dcur) {
    __shared__ int tmp[NBINS];
    const int tid = threadIdx.x;
    int v = dh[tid];
    tmp[tid] = v;
    __syncthreads();
    for (int d = 1; d < NBINS; d <<= 1) {
        int t = (tid >= d) ? tmp[tid - d] : 0;
        __syncthreads();
        tmp[tid] += t;
        __syncthreads();
    }
    int excl = tmp[tid] - v;
    dh[tid] = excl;
    dcur[tid] = excl;
}

// ord[p] = node at global position p; posOf[4n+g] = p (inverse permutation)
__global__ void __launch_bounds__(256)
deg_scatter_kernel(const int* __restrict__ cnt2, int* __restrict__ dcur,
                   int* __restrict__ ord, int* __restrict__ posOf) {
    __shared__ int lcnt[NBINS];
    __shared__ int lbase[NBINS];
    __shared__ u16 lrank[1024];
    __shared__ u16 lcls[1024];
    const int tid = threadIdx.x;
    for (int i = tid; i < NBINS; i += 256) lcnt[i] = 0;
    __syncthreads();
    const int n = blockIdx.x * 256 + tid;
    if (n < N_NODES) {
        int4 c4 = *(const int4*)(cnt2 + 4 * n);
        const int sb = (n / SLICE_N) * 32;
        int dg[4] = { c4.x, c4.y, c4.z, c4.w };
#pragma unroll
        for (int g = 0; g < 4; ++g) {
            int c = g * 256 + sb + min(dg[g], 31);
            lcls[tid * 4 + g]  = (u16)c;
            lrank[tid * 4 + g] = (u16)atomicAdd(&lcnt[c], 1);
        }
    }
    __syncthreads();
    for (int i = tid; i < NBINS; i += 256)
        lbase[i] = lcnt[i] ? atomicAdd(&dcur[i], lcnt[i]) : 0;
    __syncthreads();
    if (n < N_NODES) {
#pragma unroll
        for (int g = 0; g < 4; ++g) {
            int c = lcls[tid * 4 + g];
            int p = lbase[c] + lrank[tid * 4 + g];
            ord[p] = n;
            posOf[4 * n + g] = p;
        }
    }
}

// cursor2[key] = offp[posOf[key]]
__global__ void __launch_bounds__(256)
cursor_init_kernel(const int* __restrict__ offp, const int* __restrict__ posOf,
                   int* __restrict__ cursor2) {
    int k = blockIdx.x * 256 + threadIdx.x;
    if (k < KEYS) cursor2[k] = offp[posOf[k]];
}

// ===========================================================================
// K4: XCD-sliced gather. Lanes = (parity r in 0..3, 16 float2 channel pairs):
// 4 edges/chain in flight (32 lines/wave) + software-pipelined csr prefetch
// (iteration t+1's indices load while iteration t's rows sum) -> one L2
// latency class per trip. Partials stored as packed bf16 (2 per u32).
// ===========================================================================
__global__ void __launch_bounds__(256)
gatherP_kernel(const float* __restrict__ x, const int* __restrict__ offp,
               const int* __restrict__ csr, const int* __restrict__ ord,
               u16* __restrict__ P0, u16* __restrict__ P1,
               u16* __restrict__ P2, u16* __restrict__ P3) {
    const int sid = blockIdx.x & (NXCD - 1);
    const int g = sid >> 1;
    const int h = sid & 1;
    u16* __restrict__ P = (g == 0) ? P0 : (g == 1) ? P1 : (g == 2) ? P2 : P3;
    const int chunk = blockIdx.x >> 3;          // < GCH
    const int wid  = threadIdx.x >> 6;
    const int lane = threadIdx.x & 63;
    const int r  = lane >> 4;                   // parity 0..3
    const int cc = lane & 15;                   // float2 channel pair
    const float2* __restrict__ xs = (const float2*)x + h * 16 + cc;  // + q*32
    const int* __restrict__ ordg = ord + g * N_NODES;
    const int* __restrict__ offg = offp + g * N_NODES;

    for (int gi = wid; gi < GPB; gi += 4) {
        const int p0 = (chunk + gi * GCH) * 8;
        int j[8], e[8];
        float2 s[8];
        int lenmin = 0x7FFFFFFF;
#pragma unroll
        for (int i = 0; i < 8; ++i) {
            int a = offg[p0 + i];
            int b = offg[p0 + i + 1];
            j[i] = a + r;
            e[i] = b;
            lenmin = min(lenmin, b - a);
            s[i] = make_float2(0.f, 0.f);
        }

        // uniform part: all 8 chains valid, stride 4, csr prefetched 1 deep
        const int T = (lenmin - r + 3) >> 2;
        if (T > 0) {
            int q[8];
#pragma unroll
            for (int i = 0; i < 8; ++i) q[i] = csr[j[i]];
            for (int t = 1; t < T; ++t) {
                int qn[8];
#pragma unroll
                for (int i = 0; i < 8; ++i) qn[i] = csr[j[i] + 4 * t];
#pragma unroll
                for (int i = 0; i < 8; ++i) {
                    float2 v = xs[(size_t)q[i] * 32];
                    s[i].x += v.x; s[i].y += v.y;
                    q[i] = qn[i];
                }
            }
#pragma unroll
            for (int i = 0; i < 8; ++i) {
                float2 v = xs[(size_t)q[i] * 32];
                s[i].x += v.x; s[i].y += v.y;
                j[i] += 4 * T;
            }
        }

        // tail: odd remainders, boundary groups, class-31 overflow
        while (true) {
            bool p[8];
            bool any = false;
#pragma unroll
            for (int i = 0; i < 8; ++i) { p[i] = j[i] < e[i]; any = any || p[i]; }
            if (!any) break;
            float2 t[8];
#pragma unroll
            for (int i = 0; i < 8; ++i) {
                int q = csr[p[i] ? j[i] : 0];
                t[i] = xs[(size_t)q * 32];
            }
#pragma unroll
            for (int i = 0; i < 8; ++i) {
                if (p[i]) { s[i].x += t[i].x; s[i].y += t[i].y; }
                j[i] += 4;
            }
        }

        // reduce across 4 parities
#pragma unroll
        for (int i = 0; i < 8; ++i) {
            s[i].x += __shfl_xor(s[i].x, 16);
            s[i].x += __shfl_xor(s[i].x, 32);
            s[i].y += __shfl_xor(s[i].y, 16);
            s[i].y += __shfl_xor(s[i].y, 32);
        }
        if (r == 0) {
#pragma unroll
            for (int i = 0; i < 8; ++i) {
                int n = ordg[p0 + i];
                u32 pk = ((u32)f2bf(s[i].y) << 16) | (u32)f2bf(s[i].x);
                __builtin_nontemporal_store(pk,
                    (u32*)&P[(size_t)n * C + h * 32 + 2 * cc]);
            }
        }
    }
}

// ===========================================================================
// K5: GEMM [mean|x](100K x 128) @ [Wl;Wr]^T via mfma_f32_16x16x32_bf16.
// P partials are bf16; sum 4, scale by 1/deg, feed MFMA. Fused
// bias+relu+L2norm epilogue. One 16-node tile per wave (grid 1563).
// ===========================================================================
__global__ void __launch_bounds__(256)
transform_mfma_kernel(const float* __restrict__ x, const int* __restrict__ degT,
                      const u16* __restrict__ P0, const u16* __restrict__ P1,
                      const u16* __restrict__ P2, const u16* __restrict__ P3,
                      const float* __restrict__ Wl, const float* __restrict__ bl,
                      const float* __restrict__ Wr, float* __restrict__ out) {
    const int lane = threadIdx.x & 63;
    const int wid  = threadIdx.x >> 6;
    const int col  = lane & 15;
    const int lg   = lane >> 4;

    bf16x8 Bf[4][4];
    float bias[4];
#pragma unroll
    for (int cb = 0; cb < 4; ++cb) {
        const int cc = cb * 16 + col;
        bias[cb] = bl[cc];
#pragma unroll
        for (int ks = 0; ks < 4; ++ks) {
            const int kk0 = ks * 32 + lg * 8;
            const float* W = (kk0 < 64) ? (Wl + (size_t)cc * 64 + kk0)
                                        : (Wr + (size_t)cc * 64 + (kk0 - 64));
            float4 w0 = *(const float4*)W;
            float4 w1 = *(const float4*)(W + 4);
            bf16x8 b;
            b[0]=(short)f2bf(w0.x); b[1]=(short)f2bf(w0.y);
            b[2]=(short)f2bf(w0.z); b[3]=(short)f2bf(w0.w);
            b[4]=(short)f2bf(w1.x); b[5]=(short)f2bf(w1.y);
            b[6]=(short)f2bf(w1.z); b[7]=(short)f2bf(w1.w);
            Bf[cb][ks] = b;
        }
    }

    const int ntiles = N_NODES / 16;
    for (int t = blockIdx.x * 4 + wid; t < ntiles; t += gridDim.x * 4) {
        const int n0 = t * 16;
        const int arow = n0 + col;
        const int deg = degT[arow];
        const float inv = 1.0f / (float)(deg > 1 ? deg : 1);

        f32x4 acc[4];
#pragma unroll
        for (int cb = 0; cb < 4; ++cb) acc[cb] = f32x4{0.f, 0.f, 0.f, 0.f};

#pragma unroll
        for (int ks = 0; ks < 4; ++ks) {
            const int kk0 = ks * 32 + lg * 8;
            bf16x8 a;
            if (kk0 < 64) {
                const size_t base = (size_t)arow * C + kk0;
                u16x8 q0 = *(const u16x8*)(P0 + base);
                u16x8 q1 = *(const u16x8*)(P1 + base);
                u16x8 q2 = *(const u16x8*)(P2 + base);
                u16x8 q3 = *(const u16x8*)(P3 + base);
#pragma unroll
                for (int e2 = 0; e2 < 8; ++e2) {
                    float sum = (bf2f(q0[e2]) + bf2f(q1[e2]))
                              + (bf2f(q2[e2]) + bf2f(q3[e2]));
                    a[e2] = (short)f2bf(sum * inv);
                }
            } else {
                const float4* xp = (const float4*)(x + (size_t)arow * C + (kk0 - 64));
                float4 v0 = xp[0], v1 = xp[1];
                a[0]=(short)f2bf(v0.x); a[1]=(short)f2bf(v0.y);
                a[2]=(short)f2bf(v0.z); a[3]=(short)f2bf(v0.w);
                a[4]=(short)f2bf(v1.x); a[5]=(short)f2bf(v1.y);
                a[6]=(short)f2bf(v1.z); a[7]=(short)f2bf(v1.w);
            }
#pragma unroll
            for (int cb = 0; cb < 4; ++cb)
                acc[cb] = __builtin_amdgcn_mfma_f32_16x16x32_bf16(a, Bf[cb][ks], acc[cb], 0, 0, 0);
        }

#pragma unroll
        for (int jj = 0; jj < 4; ++jj) {
            float v0 = fmaxf(acc[0][jj] + bias[0], 0.0f);
            float v1 = fmaxf(acc[1][jj] + bias[1], 0.0f);
            float v2 = fmaxf(acc[2][jj] + bias[2], 0.0f);
            float v3 = fmaxf(acc[3][jj] + bias[3], 0.0f);
            float sS = (v0 * v0 + v1 * v1) + (v2 * v2 + v3 * v3);
            sS += __shfl_xor(sS, 1);
            sS += __shfl_xor(sS, 2);
            sS += __shfl_xor(sS, 4);
            sS += __shfl_xor(sS, 8);
            float rr = 1.0f / (sqrtf(sS) + EPS);
            const int n = n0 + lg * 4 + jj;
            float* o = out + (size_t)n * C + col;
            o[0]  = v0 * rr;
            o[16] = v1 * rr;
            o[32] = v2 * rr;
            o[48] = v3 * rr;
        }
    }
}

// ===========================================================================
extern "C" void kernel_launch(void* const* d_in, const int* in_sizes, int n_in,
                              void* d_out, int out_size, void* d_ws, size_t ws_size,
                              hipStream_t stream) {
    const float* x    = (const float*)d_in[0];
    const int*   edge = (const int*)d_in[1];
    const float* Wl   = (const float*)d_in[2];
    const float* bl   = (const float*)d_in[3];
    const float* Wr   = (const float*)d_in[4];

    const int E = in_sizes[1] / 2;
    const int* src = edge;
    const int* dst = edge + E;
    const int Epad = (E + 3) & ~3;
    const int bcap = E / NXCD + 32768;

    const size_t nc = (size_t)N_NODES * C;

    // layout: P0..P3 (bf16) | cnt2 bcur dh dcur degT posOf cursor2 offp bsum
    //         csr ord | bsrc bkey16
    u16* P0      = (u16*)d_ws;             // nc u16 each
    u16* P1      = P0 + nc;
    u16* P2      = P1 + nc;
    u16* P3      = P2 + nc;
    int* cnt2    = (int*)(P3 + nc);        // KEYS
    int* bcur    = cnt2 + KEYS;            // 8
    int* dh      = bcur + 8;               // NBINS
    int* dcur    = dh + NBINS;             // NBINS
    int* degT    = dcur + NBINS;           // N
    int* posOf   = degT + N_NODES;         // KEYS
    int* cursor2 = posOf + KEYS;           // KEYS
    int* offp    = cursor2 + KEYS;         // KEYS+4 reserved
    int* bsum    = offp + KEYS + 4;        // 512
    int* csr     = bsum + 512;             // Epad
    int* ord     = csr + Epad;             // KEYS
    int* bsrc    = ord + KEYS;             // 8*bcap
    u16* bkey16  = (u16*)(bsrc + (size_t)8 * bcap);

    const size_t baseInts = (size_t)KEYS * 5 + 8 + 2 * NBINS + N_NODES + 4 + 512 + Epad;
    const size_t needB = 4ull * nc * 2 + baseInts * 4;
    const size_t needA = needB + (size_t)8 * bcap * 6;

    // zero cnt2 + bcur + dh (adjacent); dcur seeded by scan_deg
    hipMemsetAsync(cnt2, 0, (size_t)(KEYS + 8 + NBINS) * sizeof(int), stream);

    bool tierA = (ws_size >= needA);
    if (tierA) {
        partition_kernel<<<1024, 256, 0, stream>>>(src, dst, bcur, bkey16, bsrc, E, bcap);
        hist2p_kernel<<<NXCD * 256, 256, 0, stream>>>(bcur, bkey16, cnt2, bcap);
    } else {
        hist2_kernel<<<NXCD * 256, 256, 0, stream>>>(src, dst, cnt2, E);
    }

    // slice-local degree-class ordering + permuted scan
    deg_class_kernel<<<NDH, 256, 0, stream>>>(cnt2, dh, degT);
    scan_deg_kernel<<<1, NBINS, 0, stream>>>(dh, dcur);
    deg_scatter_kernel<<<NDH, 256, 0, stream>>>(cnt2, dcur, ord, posOf);
    scan_block_perm_kernel<<<NBLKK, SCAN_BLK, 0, stream>>>(ord, cnt2, offp, bsum, KEYS);
    scan_bsum_kernel<<<1, 512, 0, stream>>>(bsum, NBLKK);
    scan_add_kernel<<<NBLKK, SCAN_BLK, 0, stream>>>(offp, bsum, KEYS, E);
    cursor_init_kernel<<<(KEYS + 255) / 256, 256, 0, stream>>>(offp, posOf, cursor2);

    if (tierA) {
        build_pass_kernel<<<NXCD * 256, 256, 0, stream>>>(bcur, bkey16, bsrc, cnt2,
                                                          cursor2, csr, bcap, 0, 4);
        build_pass_kernel<<<NXCD * 256, 256, 0, stream>>>(bcur, bkey16, bsrc, cnt2,
                                                          cursor2, csr, bcap, 4, 5);
        build_pass_kernel<<<NXCD * 256, 256, 0, stream>>>(bcur, bkey16, bsrc, cnt2,
                                                          cursor2, csr, bcap, 5, 7);
        build_pass_kernel<<<NXCD * 256, 256, 0, stream>>>(bcur, bkey16, bsrc, cnt2,
                                                          cursor2, csr, bcap, 7, 32);
    } else {
        build2_kernel<<<NXCD * 256, 256, 0, stream>>>(src, dst, cursor2, csr, E);
    }

    gatherP_kernel<<<NXCD * GCH, 256, 0, stream>>>(x, offp, csr, ord, P0, P1, P2, P3);
    transform_mfma_kernel<<<1563, 256, 0, stream>>>(x, degT, P0, P1, P2, P3,
                                                    Wl, bl, Wr, (float*)d_out);
}